// Round 4
// baseline (818.648 us; speedup 1.0000x reference)
//
#include <hip/hip_runtime.h>
#include <cstdint>
#include <cstddef>

// Problem constants
#define B_   32
#define L_   1024
#define D_   512
#define M_   (B_ * L_)   // 32768 rows (b*L + l)
#define N8D  4096        // 8*D columns of U
#define SCALEF 1.4142135623730951f
#define LOG2E 1.4426950408889634f

typedef unsigned short u16;
typedef __bf16 bf16x8 __attribute__((ext_vector_type(8)));
typedef unsigned short u16x8 __attribute__((ext_vector_type(8)));
typedef unsigned short u16x4 __attribute__((ext_vector_type(4)));
typedef float f32x4 __attribute__((ext_vector_type(4)));

__device__ __forceinline__ float bf2f(u16 u) {
    union { unsigned int i; float f; } v; v.i = ((unsigned int)u) << 16; return v.f;
}
__device__ __forceinline__ u16 f2bf(float x) {
    union { float f; unsigned int i; } v; v.f = x;
    unsigned int r = (v.i + 0x7fffu + ((v.i >> 16) & 1u)) >> 16;
    return (u16)r;
}
// fast sigmoid: v_exp_f32 + v_rcp_f32 (≈1 ulp f32 — far below bf16 noise)
__device__ __forceinline__ float sigmoid_fast(float z) {
    return __builtin_amdgcn_rcpf(1.0f + __builtin_amdgcn_exp2f(-LOG2E * z));
}

// async global->LDS, 16 bytes per lane. LDS dest = wave-uniform base + lane*16.
__device__ __forceinline__ void gl2lds16(const u16* g, u16* l) {
    __builtin_amdgcn_global_load_lds(
        (const __attribute__((address_space(1))) void*)g,
        (__attribute__((address_space(3))) void*)l, 16, 0, 0);
}

#define VMW(n) asm volatile("s_waitcnt vmcnt(" #n ")" ::: "memory")
#define LGK(n) asm volatile("s_waitcnt lgkmcnt(" #n ")" ::: "memory")
#define SB     __builtin_amdgcn_sched_barrier(0)

// ---------------- f32 -> bf16 convert (seqs), 8 elems/thread ----------------
__global__ __launch_bounds__(256) void f32_to_bf16(const float* __restrict__ in,
                                                   u16* __restrict__ out) {
    size_t i = ((size_t)blockIdx.x * 256 + threadIdx.x) * 8;
    f32x4 v0 = *(const f32x4*)(in + i);
    f32x4 v1 = *(const f32x4*)(in + i + 4);
    u16x8 o;
#pragma unroll
    for (int q = 0; q < 4; ++q) { o[q] = f2bf(v0[q]); o[4 + q] = f2bf(v1[q]); }
    *(u16x8*)(out + i) = o;
}

// ---------------- transpose W (K,4096) f32 -> WT bf16, rows PERMUTED ----------
// Physical WT row p holds logical W column n:  n = dir*2048 + comp*512 + d
//   -> p = dir*2048 + d*4 + comp   (GEMM output columns land scan-interleaved)
__global__ __launch_bounds__(256) void transpose_w(const float* __restrict__ in,
                                                   u16* __restrict__ out,
                                                   int R, int C) {
    __shared__ u16 tile[32][33];
    int bx = blockIdx.x * 32;
    int by = blockIdx.y * 32;
    int tx = threadIdx.x & 31;
    int ty = threadIdx.x >> 5;
#pragma unroll
    for (int i = 0; i < 32; i += 8)
        tile[ty + i][tx] = f2bf(in[(size_t)(by + ty + i) * C + bx + tx]);
    __syncthreads();
#pragma unroll
    for (int i = 0; i < 32; i += 8) {
        int n = bx + ty + i;
        int p = (n >> 11) * 2048 + ((n & 511) << 2) + ((n >> 9) & 3);
        out[(size_t)p * R + by + tx] = tile[tx][ty + i];
    }
}

// ---------------- GEMM 256x256x64, merged 2-phase/K-tile, counted lgkm ------
// U(M,4096) = A(M,K) * BT(4096,K)^T, all bf16.
// 8 waves (2M x 4N), per-wave out 128x64. LDS 128 KiB:
//   [buf:2][op A/B:2][kslice:2] regions of [256 rows][32 cols] bf16 (16 KiB).
// Swizzle (involution): physical byte P = L ^ ((L>>3)&0x30); staging keeps a
// LINEAR LDS dest + inverse-swizzled GLOBAL source; reads fold the same XOR.
// PHASE (one per buf,kslice; 2 per K-tile): 12 ds_read_b128 issued in PINNED
// order (B0..3, A0..7, sched_barrier(0) after each), then 8 MFMA groups of 4,
// group g gated by lgkmcnt(7-g) — read g+5 lands while group g-? computes, so
// the LDS port overlaps the MFMA pipe instead of alternating with it (the
// measured failure mode of the 8-phase version: 620cy MFMA + ~860cy serial
// LDS per phase, MfmaUtil stuck at 42%).
// Barrier ledger (1 barrier + 1 VMW per phase): phase(t,ks) stages tile t+1's
// (A,ks)+(B,ks) into buf^1.  RAW: VMW(4) at phase end waits the 4 calls of the
// PREVIOUS phase (exactly the regions the NEXT phase reads), barrier
// broadcasts.  WAR: a region staged at phase(t+1,ks) was last read at
// phase(t,ks), whose reads completed at its own lgkmcnt(0) before >=1
// intervening barrier.  Peel: VMW(0) at (nt-1,0), nothing at (nt-1,1).
__global__ __launch_bounds__(512, 2) void gemm256(const u16* __restrict__ A,
                                                  const u16* __restrict__ BT,
                                                  u16* __restrict__ U, int K) {
    extern __shared__ __align__(16) u16 lds[];   // 65536 u16 = 128 KiB
    const int t    = threadIdx.x;
    const int lane = t & 63;
    const int wave = t >> 6;
    const int wm   = wave >> 2;        // 0..1
    const int wn   = wave & 3;         // 0..3
    const int qm   = lane & 15;
    const int quad = lane >> 4;

    // T1: XCD-contiguous block swizzle (2048 blocks, 8 XCDs, bijective)
    const int nwg = gridDim.x;
    const int wg  = blockIdx.x;
    const int swz = (wg & 7) * (nwg >> 3) + (wg >> 3);
    const int bn  = (swz & 15) << 8;   // 16 N-tiles (fast: A-tile reuse in L2)
    const int bm  = (swz >> 4) << 8;   // 128 M-tiles

    // staging: thread t owns physical region bytes [t*16, t*16+16);
    // logical position L = P ^ ((P>>3)&0x30)  (self-inverse XOR)
    const int P0   = t * 16;
    const int L0   = P0 ^ ((P0 >> 3) & 0x30);
    const int srow = L0 >> 6;           // 0..127
    const int scol = (L0 & 63) >> 1;    // 0..31 u16, multiple of 8
    const u16* Ag = A  + (size_t)(bm + srow) * K + scol;
    const u16* Bg = BT + (size_t)(bn + srow) * K + scol;
    const size_t g128 = (size_t)128 * K;
    u16* ldst = lds + t * 8;            // linear dest: region base + t*16 bytes

    // fragment-read lane bases (bytes within a 16 KiB region), XOR folded in
    const int fxor  = (quad * 16) ^ ((qm & 6) << 3);
    const int aBase = (wm * 128 + qm) * 64 + fxor;
    const int bBase = (wn * 64  + qm) * 64 + fxor;
    const char* ldsc = (const char*)lds;

    f32x4 acc[8][4];
#pragma unroll
    for (int i = 0; i < 8; ++i)
#pragma unroll
        for (int j = 0; j < 4; ++j) acc[i][j] = (f32x4)(0.0f);

#define RD16(p) (*(const bf16x8*)(p))

// stage region (op,ks) of 'tile' into buffer 'buf' (2 gl2lds calls, 16 KiB)
#define STGR(op, tile, ks, buf) do {                                         \
        const u16* g_ = ((op) ? Bg : Ag) + (size_t)(tile) * 64 + (ks) * 32;  \
        u16* l_ = ldst + (buf) * 32768 + (op) * 16384 + (ks) * 8192;         \
        gl2lds16(g_, l_);                                                    \
        gl2lds16(g_ + g128, l_ + 4096);                                      \
    } while (0)

#define G4(g, av) do {                                                       \
        _Pragma("unroll")                                                    \
        for (int nj = 0; nj < 4; ++nj)                                       \
            acc[g][nj] = __builtin_amdgcn_mfma_f32_16x16x32_bf16(            \
                av, bb[nj], acc[g][nj], 0, 0, 0);                            \
    } while (0)

// one phase: buf,ks literals; stile may be runtime; dostage/vmn/dobar literals
#define PH(buf, ks, stile, dostage, vmn, dobar) do {                         \
        const char* As_ = ldsc + ((buf) * 32768 + (ks) * 8192) * 2;          \
        const char* Bs_ = ldsc + ((buf) * 32768 + 16384 + (ks) * 8192) * 2;  \
        bf16x8 bb[4], aa[8];                                                 \
        bb[0] = RD16(Bs_ + bBase);        SB;                                \
        bb[1] = RD16(Bs_ + bBase + 1024); SB;                                \
        bb[2] = RD16(Bs_ + bBase + 2048); SB;                                \
        bb[3] = RD16(Bs_ + bBase + 3072); SB;                                \
        aa[0] = RD16(As_ + aBase);        SB;                                \
        aa[1] = RD16(As_ + aBase + 1024); SB;                                \
        aa[2] = RD16(As_ + aBase + 2048); SB;                                \
        aa[3] = RD16(As_ + aBase + 3072); SB;                                \
        aa[4] = RD16(As_ + aBase + 4096); SB;                                \
        aa[5] = RD16(As_ + aBase + 5120); SB;                                \
        aa[6] = RD16(As_ + aBase + 6144); SB;                                \
        aa[7] = RD16(As_ + aBase + 7168); SB;                                \
        if (dostage) { STGR(0, stile, ks, (buf) ^ 1);                        \
                       STGR(1, stile, ks, (buf) ^ 1); }                      \
        __builtin_amdgcn_s_setprio(1);                                       \
        LGK(7); SB; G4(0, aa[0]); SB;                                        \
        LGK(6); SB; G4(1, aa[1]); SB;                                        \
        LGK(5); SB; G4(2, aa[2]); SB;                                        \
        LGK(4); SB; G4(3, aa[3]); SB;                                        \
        LGK(3); SB; G4(4, aa[4]); SB;                                        \
        LGK(2); SB; G4(5, aa[5]); SB;                                        \
        LGK(1); SB; G4(6, aa[6]); SB;                                        \
        LGK(0); SB; G4(7, aa[7]); SB;                                        \
        __builtin_amdgcn_s_setprio(0);                                       \
        if ((vmn) == 4) VMW(4); else if ((vmn) == 0) VMW(0);                 \
        if (dobar) { SB; __builtin_amdgcn_s_barrier(); SB; }                 \
    } while (0)

    const int nt = K >> 6;   // 8 (K=512) or 16 (K=1024)

    // prologue: stage tile0 fully (8 calls); wait its ks0 regions; barrier
    STGR(0, 0, 0, 0); STGR(1, 0, 0, 0); STGR(0, 0, 1, 0); STGR(1, 0, 1, 0);
    VMW(4);
    __builtin_amdgcn_s_barrier();

    for (int i = 0; i < (nt >> 1) - 1; ++i) {
        const int t2 = 2 * i;
        PH(0, 0, t2 + 1, 1, 4, 1);
        PH(0, 1, t2 + 1, 1, 4, 1);
        PH(1, 0, t2 + 2, 1, 4, 1);
        PH(1, 1, t2 + 2, 1, 4, 1);
    }
    // peel: tile nt-2 (buf0) stages nt-1; tile nt-1 (buf1) drains
    PH(0, 0, nt - 1, 1, 4, 1);
    PH(0, 1, nt - 1, 1, 4, 1);
    PH(1, 0, 0, 0, 0, 1);
    PH(1, 1, 0, 0, -1, 0);

#undef PH
#undef G4
#undef STGR
#undef RD16

    // epilogue: C/D layout col=lane&15, row=quad*4+reg; acc[i8] is row-frag
    // offset (i8>>2)*64 + (i8&3)*16
#pragma unroll
    for (int i8 = 0; i8 < 8; ++i8) {
        const int row0 = bm + wm * 128 + (i8 >> 2) * 64 + (i8 & 3) * 16 + quad * 4;
#pragma unroll
        for (int nj = 0; nj < 4; ++nj) {
            const int col = bn + wn * 64 + nj * 16 + qm;
#pragma unroll
            for (int r = 0; r < 4; ++r)
                U[(size_t)(row0 + r) * N8D + col] = f2bf(acc[i8][nj][r]);
        }
    }
}

// ---------------- SRU scan: one thread per (b, dir, d) ----------------
// U (interleaved): (b*L+l)*4096 + dir*2048 + d*4 + {0:xt,1:fp,2:rp,3:xp}
// H: (b*L+l)*1024 + dir*512 + d ; C: b*1024 + dir*512 + d
// PF=32 ping-pong prefetch: batch t+1 loads issue BEFORE batch t compute, so
// vmcnt waits for loads never drain the (shared-counter) h-stores.
// Grid 512x64: 32768 threads over all 256 CUs (2 blocks/CU).
template<bool OUT_F32>
__global__ __launch_bounds__(64) void sru_scan(const u16* __restrict__ U,
                                               const float* __restrict__ vf,
                                               const float* __restrict__ vr,
                                               const float* __restrict__ bfv,
                                               const float* __restrict__ brv,
                                               void* __restrict__ Hv,
                                               void* __restrict__ Cv) {
    constexpr int PF = 32;
    constexpr int NB = L_ / PF;  // 32 batches

    int gid = blockIdx.x * blockDim.x + threadIdx.x;  // 0..32767
    int d   = gid & (D_ - 1);
    int dir = (gid >> 9) & 1;   // uniform within a 64-thread block
    int b   = gid >> 10;
    int ch  = dir * D_ + d;

    const float vf_v = vf[ch];
    const float vr_v = vr[ch];
    const float bf_v = bfv[ch];
    const float br_v = brv[ch];

    // direction-adjusted start pointers + signed element steps
    const ptrdiff_t ustep = dir ? -(ptrdiff_t)N8D : (ptrdiff_t)N8D;
    const ptrdiff_t hstep = dir ? -(ptrdiff_t)1024 : (ptrdiff_t)1024;
    const u16* p0 = U + (size_t)b * L_ * N8D + dir * 2048 + d * 4
                      + (dir ? (size_t)(L_ - 1) * N8D : 0);
    const size_t hstart = (size_t)b * L_ * 1024 + ch + (dir ? (size_t)(L_ - 1) * 1024 : 0);
    float* Hf = (float*)Hv + hstart;
    u16*   Hh = (u16*)Hv + hstart;

    float c = 0.0f;

    auto loadB = [&](u16x4 (&buf)[PF], int tb) {
        const u16* base = p0 + (ptrdiff_t)tb * PF * ustep;
#pragma unroll
        for (int i = 0; i < PF; ++i)
            buf[i] = *(const u16x4*)(base + (ptrdiff_t)i * ustep);
    };
    auto compStore = [&](u16x4 (&buf)[PF], int tb) {
        const ptrdiff_t hb = (ptrdiff_t)tb * PF * hstep;
#pragma unroll
        for (int i = 0; i < PF; ++i) {
            float xt = bf2f(buf[i][0]), fp = bf2f(buf[i][1]);
            float rp = bf2f(buf[i][2]), xp = bf2f(buf[i][3]);
            float f = sigmoid_fast(fp + vf_v * c + bf_v);
            float r = sigmoid_fast(rp + vr_v * c + br_v);
            c = f * (c - xt) + xt;                 // f*c + (1-f)*xt
            float xs = xp * SCALEF;
            float h  = r * (c - xs) + xs;          // r*c + (1-r)*xp*SCALE
            ptrdiff_t ho = hb + (ptrdiff_t)i * hstep;
            if (OUT_F32) Hf[ho] = h; else Hh[ho] = f2bf(h);
        }
    };

    u16x4 b0[PF], b1[PF];
    loadB(b0, 0);
    loadB(b1, 1);
    for (int t = 0; t < NB; t += 2) {
        compStore(b0, t);
        if (t + 2 < NB) loadB(b0, t + 2);
        compStore(b1, t + 1);
        if (t + 3 < NB) loadB(b1, t + 3);
    }

    if (OUT_F32) ((float*)Cv)[b * 1024 + ch] = c;
    else         ((u16*)Cv)[b * 1024 + ch]  = f2bf(c);
}

// ---------------- launch ----------------
extern "C" void kernel_launch(void* const* d_in, const int* in_sizes, int n_in,
                              void* d_out, int out_size, void* d_ws, size_t ws_size,
                              hipStream_t stream) {
    (void)in_sizes; (void)n_in; (void)out_size; (void)ws_size;

    const float* seqs = (const float*)d_in[0];
    const float* W0   = (const float*)d_in[1];
    const float* vf0  = (const float*)d_in[2];
    const float* vr0  = (const float*)d_in[3];
    const float* bf0  = (const float*)d_in[4];
    const float* br0  = (const float*)d_in[5];
    const float* W1   = (const float*)d_in[6];
    const float* vf1  = (const float*)d_in[7];
    const float* vr1  = (const float*)d_in[8];
    const float* bf1  = (const float*)d_in[9];
    const float* br1  = (const float*)d_in[10];
    // d_in[11] = lengths : unused by the reference

    float* out = (float*)d_out;  // [c1: 32*1024 f32][out1: 32*1024*1024 f32]
    char* ws = (char*)d_ws;

    const size_t U_BYTES  = (size_t)M_ * N8D * 2;        // 268435456
    const size_t H_BYTES  = (size_t)M_ * 1024 * 2;       // 67108864
    const size_t W0T_B    = (size_t)4096 * 512 * 2;      // 4194304
    const size_t W1T_B    = (size_t)4096 * 1024 * 2;     // 8388608

    u16* U   = (u16*)(ws);
    u16* H0  = (u16*)(ws + U_BYTES);               // also holds seqs_bf16 before scan0
    u16* S16 = H0;                                  // dead after gemm0
    u16* W0T = (u16*)(ws + U_BYTES + H_BYTES);
    u16* W1T = (u16*)(ws + U_BYTES + H_BYTES + W0T_B);
    u16* Cd  = (u16*)(ws + U_BYTES + H_BYTES + W0T_B + W1T_B);  // dummy c, layer 0

    // seqs f32 -> bf16
    f32_to_bf16<<<dim3(M_ * 512 / 8 / 256), 256, 0, stream>>>(seqs, S16);

    // W0 (512,4096) f32 -> W0T bf16 (permuted rows); W1 (1024,4096) -> W1T
    transpose_w<<<dim3(4096 / 32, 512 / 32), 256, 0, stream>>>(W0, W0T, 512, 4096);
    transpose_w<<<dim3(4096 / 32, 1024 / 32), 256, 0, stream>>>(W1, W1T, 1024, 4096);

    // Layer 0: A = seqs_bf16, K=512
    gemm256<<<dim3(2048), 512, 131072, stream>>>(S16, W0T, U, 512);
    sru_scan<false><<<dim3(512), 64, 0, stream>>>(U, vf0, vr0, bf0, br0, (void*)H0, (void*)Cd);

    // Layer 1: A = H0 (bf16), K=1024
    gemm256<<<dim3(2048), 512, 131072, stream>>>(H0, W1T, U, 1024);
    sru_scan<true><<<dim3(512), 64, 0, stream>>>(U, vf1, vr1, bf1, br1,
                                                 (void*)(out + B_ * 1024), (void*)out);
}

// Round 5
// 807.534 us; speedup vs baseline: 1.0138x; 1.0138x over previous
//
#include <hip/hip_runtime.h>
#include <cstdint>
#include <cstddef>

// Problem constants
#define B_   32
#define L_   1024
#define D_   512
#define M_   (B_ * L_)   // 32768 rows (b*L + l)
#define N8D  4096        // 8*D columns of U
#define SCALEF 1.4142135623730951f
#define LOG2E 1.4426950408889634f

typedef unsigned short u16;
typedef __bf16 bf16x8 __attribute__((ext_vector_type(8)));
typedef unsigned short u16x8 __attribute__((ext_vector_type(8)));
typedef unsigned short u16x4 __attribute__((ext_vector_type(4)));
typedef float f32x4 __attribute__((ext_vector_type(4)));

__device__ __forceinline__ float bf2f(u16 u) {
    union { unsigned int i; float f; } v; v.i = ((unsigned int)u) << 16; return v.f;
}
__device__ __forceinline__ u16 f2bf(float x) {
    union { float f; unsigned int i; } v; v.f = x;
    unsigned int r = (v.i + 0x7fffu + ((v.i >> 16) & 1u)) >> 16;
    return (u16)r;
}
// fast sigmoid: v_exp_f32 + v_rcp_f32 (≈1 ulp f32 — far below bf16 noise)
__device__ __forceinline__ float sigmoid_fast(float z) {
    return __builtin_amdgcn_rcpf(1.0f + __builtin_amdgcn_exp2f(-LOG2E * z));
}

// async global->LDS, 16 bytes per lane. LDS dest = wave-uniform base + lane*16.
__device__ __forceinline__ void gl2lds16(const u16* g, u16* l) {
    __builtin_amdgcn_global_load_lds(
        (const __attribute__((address_space(1))) void*)g,
        (__attribute__((address_space(3))) void*)l, 16, 0, 0);
}

#define VMW(n) asm volatile("s_waitcnt vmcnt(" #n ")" ::: "memory")
#define LGK(n) asm volatile("s_waitcnt lgkmcnt(" #n ")" ::: "memory")
#define SB     __builtin_amdgcn_sched_barrier(0)

// ---------------- f32 -> bf16 convert (seqs), 8 elems/thread ----------------
__global__ __launch_bounds__(256) void f32_to_bf16(const float* __restrict__ in,
                                                   u16* __restrict__ out) {
    size_t i = ((size_t)blockIdx.x * 256 + threadIdx.x) * 8;
    f32x4 v0 = *(const f32x4*)(in + i);
    f32x4 v1 = *(const f32x4*)(in + i + 4);
    u16x8 o;
#pragma unroll
    for (int q = 0; q < 4; ++q) { o[q] = f2bf(v0[q]); o[4 + q] = f2bf(v1[q]); }
    *(u16x8*)(out + i) = o;
}

// ---------------- transpose W (K,4096) f32 -> WT bf16, rows PERMUTED ----------
// Physical WT row p holds logical W column n:  n = dir*2048 + comp*512 + d
//   -> p = dir*2048 + d*4 + comp   (GEMM output columns land scan-interleaved)
__global__ __launch_bounds__(256) void transpose_w(const float* __restrict__ in,
                                                   u16* __restrict__ out,
                                                   int R, int C) {
    __shared__ u16 tile[32][33];
    int bx = blockIdx.x * 32;
    int by = blockIdx.y * 32;
    int tx = threadIdx.x & 31;
    int ty = threadIdx.x >> 5;
#pragma unroll
    for (int i = 0; i < 32; i += 8)
        tile[ty + i][tx] = f2bf(in[(size_t)(by + ty + i) * C + bx + tx]);
    __syncthreads();
#pragma unroll
    for (int i = 0; i < 32; i += 8) {
        int n = bx + ty + i;
        int p = (n >> 11) * 2048 + ((n & 511) << 2) + ((n >> 9) & 3);
        out[(size_t)p * R + by + tx] = tile[tx][ty + i];
    }
}

// ---------------- GEMM 128x256x32, 3-buffer ring, 2 blocks/CU ---------------
// U(M,4096) = A(M,K) * BT(4096,K)^T, all bf16.
// THE MECHANISM THIS ROUND: 3 schedule variants at 1 block/CU all pinned at
// MfmaUtil 42% — barrier-lockstep waves alternate read-burst / MFMA-burst and
// neither pipe fills the other's idle window. Fix = CROSS-BLOCK asynchrony
// (m114: independent waves co-schedule pipes fully): LDS cut to 72 KiB
// (3 bufs x (A 8K + B 16K)) -> 2 resident blocks/CU, mutually unsynchronized.
// Per-wave geometry UNCHANGED vs previous rounds (128x64 out, 12 ds_read_b128
// per 32 MFMA, same XOR swizzle, counted-lgkm interior, setprio).
// 4 waves (1M x 4N), 256 threads. Buffer ring: phase t computes buf t%3,
// stages tile t+2 into buf (t+2)%3 (6 gl2lds).  vmcnt ledger: end-of-phase
// VMW(6) leaves the 6 just-issued (tile t+2) and drains tile t+1 exactly;
// peel VMW(0) then nothing.  WAR: buf (t+2)%3 last read in phase t-1, drained
// at its lgkmcnt(0) >=1 barrier before the stage.  Swizzle (involution):
// physical byte P = L ^ ((P>>3)&0x30) per 64-B row; staging keeps LINEAR LDS
// dest + inverse-swizzled GLOBAL source; reads fold the same XOR (fxor).
__global__ __launch_bounds__(256, 2) void gemm128(const u16* __restrict__ A,
                                                  const u16* __restrict__ BT,
                                                  u16* __restrict__ U, int K) {
    extern __shared__ __align__(16) u16 lds[];   // 73728 B
    const int t    = threadIdx.x;      // 0..255
    const int lane = t & 63;
    const int wn   = t >> 6;           // wave 0..3 (all waves split N)
    const int qm   = lane & 15;
    const int quad = lane >> 4;

    // T1: XCD-contiguous block swizzle (4096 blocks, 8 XCDs, bijective)
    const int nwg = gridDim.x;
    const int wg  = blockIdx.x;
    const int swz = (wg & 7) * (nwg >> 3) + (wg >> 3);
    const int bn  = (swz & 15) << 8;   // 16 N-tiles of 256 (fast: L2 reuse)
    const int bm  = (swz >> 4) << 7;   // 256 M-tiles of 128

    // staging: thread t owns physical bytes [t*16, t*16+16) of each 4 KiB call
    // chunk; logical L0 = P ^ ((P>>3)&0x30) (self-inverse)
    const int P0   = t * 16;            // 0..4095
    const int L0   = P0 ^ ((P0 >> 3) & 0x30);
    const int srow = L0 >> 6;           // 0..63
    const int scol = (L0 & 63) >> 1;    // 0..31 u16, multiple of 8
    const u16* Ag = A  + (size_t)(bm + srow) * K + scol;
    const u16* Bg = BT + (size_t)(bn + srow) * K + scol;
    const size_t g64 = (size_t)64 * K;
    u16* ldst = lds + t * 8;            // linear dest base (u16), + call offs

    // fragment-read lane bases (bytes), XOR folded in
    const int fxor = (quad * 16) ^ ((qm & 6) << 3);
    const int aL   = qm * 64 + fxor;               // A region [128][32]
    const int bL   = (wn * 64 + qm) * 64 + fxor;   // B region [256][32]
    const char* ldsc = (const char*)lds;

    f32x4 acc[8][4];
#pragma unroll
    for (int i = 0; i < 8; ++i)
#pragma unroll
        for (int j = 0; j < 4; ++j) acc[i][j] = (f32x4)(0.0f);

#define RD16(p) (*(const bf16x8*)(p))

// stage tile kt into buffer at byte base bb: A (2 calls) + B (4 calls)
#define STG6(kt, bb) do {                                                    \
        const u16* a_ = Ag + (size_t)(kt) * 32;                              \
        const u16* b_ = Bg + (size_t)(kt) * 32;                              \
        u16* la = ldst + (bb) / 2;                                           \
        gl2lds16(a_,       la);                                              \
        gl2lds16(a_ + g64, la + 2048);                                       \
        u16* lb = ldst + (bb) / 2 + 4096;                                    \
        gl2lds16(b_,           lb);                                          \
        gl2lds16(b_ + g64,     lb + 2048);                                   \
        gl2lds16(b_ + 2 * g64, lb + 4096);                                   \
        gl2lds16(b_ + 3 * g64, lb + 6144);                                   \
    } while (0)

#define G4(g, av) do {                                                       \
        _Pragma("unroll")                                                    \
        for (int nj = 0; nj < 4; ++nj)                                       \
            acc[g][nj] = __builtin_amdgcn_mfma_f32_16x16x32_bf16(            \
                av, bbf[nj], acc[g][nj], 0, 0, 0);                           \
    } while (0)

// one phase on buffer byte-base bb (runtime uniform)
#define PH(bb, STAGE_STMT, VM_STMT) do {                                     \
        const char* As_ = ldsc + (bb);                                       \
        const char* Bs_ = ldsc + (bb) + 8192;                                \
        bf16x8 bbf[4], aa[8];                                                \
        bbf[0] = RD16(Bs_ + bL);        SB;                                  \
        bbf[1] = RD16(Bs_ + bL + 1024); SB;                                  \
        bbf[2] = RD16(Bs_ + bL + 2048); SB;                                  \
        bbf[3] = RD16(Bs_ + bL + 3072); SB;                                  \
        aa[0] = RD16(As_ + aL);        SB;                                   \
        aa[1] = RD16(As_ + aL + 1024); SB;                                   \
        aa[2] = RD16(As_ + aL + 2048); SB;                                   \
        aa[3] = RD16(As_ + aL + 3072); SB;                                   \
        aa[4] = RD16(As_ + aL + 4096); SB;                                   \
        aa[5] = RD16(As_ + aL + 5120); SB;                                   \
        aa[6] = RD16(As_ + aL + 6144); SB;                                   \
        aa[7] = RD16(As_ + aL + 7168); SB;                                   \
        STAGE_STMT;                                                          \
        __builtin_amdgcn_s_setprio(1);                                       \
        LGK(7); SB; G4(0, aa[0]); SB;                                        \
        LGK(6); SB; G4(1, aa[1]); SB;                                        \
        LGK(5); SB; G4(2, aa[2]); SB;                                        \
        LGK(4); SB; G4(3, aa[3]); SB;                                        \
        LGK(3); SB; G4(4, aa[4]); SB;                                        \
        LGK(2); SB; G4(5, aa[5]); SB;                                        \
        LGK(1); SB; G4(6, aa[6]); SB;                                        \
        LGK(0); SB; G4(7, aa[7]); SB;                                        \
        __builtin_amdgcn_s_setprio(0);                                       \
        VM_STMT;                                                             \
        SB; __builtin_amdgcn_s_barrier(); SB;                                \
    } while (0)

    const int nt = K >> 5;   // 16 (K=512) or 32 (K=1024)

    // prologue: stage tiles 0,1; drain tile 0 (leave tile 1's 6 in flight)
    STG6(0, 0); STG6(1, 24576);
    VMW(6);
    __builtin_amdgcn_s_barrier();

    int bb = 0, bs = 49152;   // compute base, stage base (cycle by 24576)
    for (int tt = 0; tt + 2 < nt; ++tt) {
        PH(bb, STG6(tt + 2, bs), VMW(6));
        bb += 24576; if (bb == 73728) bb = 0;
        bs += 24576; if (bs == 73728) bs = 0;
    }
    PH(bb, , VMW(0));
    bb += 24576; if (bb == 73728) bb = 0;
    PH(bb, , );

#undef PH
#undef G4
#undef STG6
#undef RD16

    // epilogue: C/D layout col=lane&15, row=quad*4+reg
#pragma unroll
    for (int i8 = 0; i8 < 8; ++i8) {
        const int row0 = bm + i8 * 16 + quad * 4;
#pragma unroll
        for (int nj = 0; nj < 4; ++nj) {
            const int col = bn + wn * 64 + nj * 16 + qm;
#pragma unroll
            for (int r = 0; r < 4; ++r)
                U[(size_t)(row0 + r) * N8D + col] = f2bf(acc[i8][nj][r]);
        }
    }
}

// ---------------- SRU scan: one thread per (b, dir, d) ----------------
// U (interleaved): (b*L+l)*4096 + dir*2048 + d*4 + {0:xt,1:fp,2:rp,3:xp}
// H: (b*L+l)*1024 + dir*512 + d ; C: b*1024 + dir*512 + d
// PF=32 ping-pong prefetch: batch t+1 loads issue BEFORE batch t compute, so
// vmcnt waits for loads never drain the (shared-counter) h-stores.
// Grid 512x64: 32768 threads over all 256 CUs (2 blocks/CU).
template<bool OUT_F32>
__global__ __launch_bounds__(64) void sru_scan(const u16* __restrict__ U,
                                               const float* __restrict__ vf,
                                               const float* __restrict__ vr,
                                               const float* __restrict__ bfv,
                                               const float* __restrict__ brv,
                                               void* __restrict__ Hv,
                                               void* __restrict__ Cv) {
    constexpr int PF = 32;
    constexpr int NB = L_ / PF;  // 32 batches

    int gid = blockIdx.x * blockDim.x + threadIdx.x;  // 0..32767
    int d   = gid & (D_ - 1);
    int dir = (gid >> 9) & 1;   // uniform within a 64-thread block
    int b   = gid >> 10;
    int ch  = dir * D_ + d;

    const float vf_v = vf[ch];
    const float vr_v = vr[ch];
    const float bf_v = bfv[ch];
    const float br_v = brv[ch];

    // direction-adjusted start pointers + signed element steps
    const ptrdiff_t ustep = dir ? -(ptrdiff_t)N8D : (ptrdiff_t)N8D;
    const ptrdiff_t hstep = dir ? -(ptrdiff_t)1024 : (ptrdiff_t)1024;
    const u16* p0 = U + (size_t)b * L_ * N8D + dir * 2048 + d * 4
                      + (dir ? (size_t)(L_ - 1) * N8D : 0);
    const size_t hstart = (size_t)b * L_ * 1024 + ch + (dir ? (size_t)(L_ - 1) * 1024 : 0);
    float* Hf = (float*)Hv + hstart;
    u16*   Hh = (u16*)Hv + hstart;

    float c = 0.0f;

    auto loadB = [&](u16x4 (&buf)[PF], int tb) {
        const u16* base = p0 + (ptrdiff_t)tb * PF * ustep;
#pragma unroll
        for (int i = 0; i < PF; ++i)
            buf[i] = *(const u16x4*)(base + (ptrdiff_t)i * ustep);
    };
    auto compStore = [&](u16x4 (&buf)[PF], int tb) {
        const ptrdiff_t hb = (ptrdiff_t)tb * PF * hstep;
#pragma unroll
        for (int i = 0; i < PF; ++i) {
            float xt = bf2f(buf[i][0]), fp = bf2f(buf[i][1]);
            float rp = bf2f(buf[i][2]), xp = bf2f(buf[i][3]);
            float f = sigmoid_fast(fp + vf_v * c + bf_v);
            float r = sigmoid_fast(rp + vr_v * c + br_v);
            c = f * (c - xt) + xt;                 // f*c + (1-f)*xt
            float xs = xp * SCALEF;
            float h  = r * (c - xs) + xs;          // r*c + (1-r)*xp*SCALE
            ptrdiff_t ho = hb + (ptrdiff_t)i * hstep;
            if (OUT_F32) Hf[ho] = h; else Hh[ho] = f2bf(h);
        }
    };

    u16x4 b0[PF], b1[PF];
    loadB(b0, 0);
    loadB(b1, 1);
    for (int t = 0; t < NB; t += 2) {
        compStore(b0, t);
        if (t + 2 < NB) loadB(b0, t + 2);
        compStore(b1, t + 1);
        if (t + 3 < NB) loadB(b1, t + 3);
    }

    if (OUT_F32) ((float*)Cv)[b * 1024 + ch] = c;
    else         ((u16*)Cv)[b * 1024 + ch]  = f2bf(c);
}

// ---------------- launch ----------------
extern "C" void kernel_launch(void* const* d_in, const int* in_sizes, int n_in,
                              void* d_out, int out_size, void* d_ws, size_t ws_size,
                              hipStream_t stream) {
    (void)in_sizes; (void)n_in; (void)out_size; (void)ws_size;

    const float* seqs = (const float*)d_in[0];
    const float* W0   = (const float*)d_in[1];
    const float* vf0  = (const float*)d_in[2];
    const float* vr0  = (const float*)d_in[3];
    const float* bf0  = (const float*)d_in[4];
    const float* br0  = (const float*)d_in[5];
    const float* W1   = (const float*)d_in[6];
    const float* vf1  = (const float*)d_in[7];
    const float* vr1  = (const float*)d_in[8];
    const float* bf1  = (const float*)d_in[9];
    const float* br1  = (const float*)d_in[10];
    // d_in[11] = lengths : unused by the reference

    float* out = (float*)d_out;  // [c1: 32*1024 f32][out1: 32*1024*1024 f32]
    char* ws = (char*)d_ws;

    const size_t U_BYTES  = (size_t)M_ * N8D * 2;        // 268435456
    const size_t H_BYTES  = (size_t)M_ * 1024 * 2;       // 67108864
    const size_t W0T_B    = (size_t)4096 * 512 * 2;      // 4194304
    const size_t W1T_B    = (size_t)4096 * 1024 * 2;     // 8388608

    u16* U   = (u16*)(ws);
    u16* H0  = (u16*)(ws + U_BYTES);               // also holds seqs_bf16 before scan0
    u16* S16 = H0;                                  // dead after gemm0
    u16* W0T = (u16*)(ws + U_BYTES + H_BYTES);
    u16* W1T = (u16*)(ws + U_BYTES + H_BYTES + W0T_B);
    u16* Cd  = (u16*)(ws + U_BYTES + H_BYTES + W0T_B + W1T_B);  // dummy c, layer 0

    // seqs f32 -> bf16
    f32_to_bf16<<<dim3(M_ * 512 / 8 / 256), 256, 0, stream>>>(seqs, S16);

    // W0 (512,4096) f32 -> W0T bf16 (permuted rows); W1 (1024,4096) -> W1T
    transpose_w<<<dim3(4096 / 32, 512 / 32), 256, 0, stream>>>(W0, W0T, 512, 4096);
    transpose_w<<<dim3(4096 / 32, 1024 / 32), 256, 0, stream>>>(W1, W1T, 1024, 4096);

    // Layer 0: A = seqs_bf16, K=512   (4096 blocks = 256 bm x 16 bn)
    gemm128<<<dim3(4096), 256, 73728, stream>>>(S16, W0T, U, 512);
    sru_scan<false><<<dim3(512), 64, 0, stream>>>(U, vf0, vr0, bf0, br0, (void*)H0, (void*)Cd);

    // Layer 1: A = H0 (bf16), K=1024
    gemm128<<<dim3(4096), 256, 73728, stream>>>(H0, W1T, U, 1024);
    sru_scan<true><<<dim3(512), 64, 0, stream>>>(U, vf1, vr1, bf1, br1,
                                                 (void*)(out + B_ * 1024), (void*)out);
}